// Round 4
// baseline (2563.564 us; speedup 1.0000x reference)
//
#include <hip/hip_runtime.h>
#include <stdint.h>

#define N_EXP  2048
#define N_DICT 65536
#define N_PIX  1600
#define TOPK   10
#define K1     16     // merged candidate list per row
#define KTH    8      // per-thread top list in merge kernel
#define K2     16     // refine set size
#define NBLK   256    // N_DICT / BN
#define NCAND  (NBLK * 8)   // candidates per row from gemm epilogue (unchanged: 2048)

#define BM 256
#define BN 256
#define BK 64
#define KT 25         // N_PIX / BK

typedef __attribute__((ext_vector_type(8))) __bf16 bf16x8;
typedef __attribute__((ext_vector_type(4))) float  f32x4;

// float -> bf16 (RNE)
__device__ __forceinline__ unsigned short f2bf(float f) {
    unsigned int u = __float_as_uint(f);
    unsigned int r = (u + 0x7FFFu + ((u >> 16) & 1u)) >> 16;
    return (unsigned short)r;
}

__device__ __forceinline__ float sel8f(const float a[8], int p) {
    float r = a[0];
    #pragma unroll
    for (int t = 1; t < 8; ++t) r = (p == t) ? a[t] : r;
    return r;
}
__device__ __forceinline__ int sel8i(const int a[8], int p) {
    int r = a[0];
    #pragma unroll
    for (int t = 1; t < 8; ++t) r = (p == t) ? a[t] : r;
    return r;
}

__device__ __forceinline__ float blockReduceSumF(float v) {
    __shared__ float p[4];
    #pragma unroll
    for (int o = 32; o > 0; o >>= 1) v += __shfl_down(v, o);
    __syncthreads();
    if ((threadIdx.x & 63) == 0) p[threadIdx.x >> 6] = v;
    __syncthreads();
    return p[0] + p[1] + p[2] + p[3];
}

// ---------------- prep: mean-subtract + normalize -> bf16 ----------------
__global__ __launch_bounds__(256) void prep_rows(const float* __restrict__ in,
                                                 unsigned short* __restrict__ outb) {
    const int row = blockIdx.x;
    const int tid = threadIdx.x;
    const float* x = in + (size_t)row * N_PIX;
    float v[7];
    float s = 0.f;
    #pragma unroll
    for (int it = 0; it < 7; ++it) {
        int j = tid + it * 256;
        float t = (j < N_PIX) ? x[j] : 0.f;
        v[it] = t; s += t;
    }
    s = blockReduceSumF(s);
    const float mean = s * (1.0f / N_PIX);
    float ss = 0.f;
    #pragma unroll
    for (int it = 0; it < 7; ++it) {
        int j = tid + it * 256;
        float c = v[it] - mean;
        if (j < N_PIX) ss += c * c;
    }
    ss = blockReduceSumF(ss);
    const float rn = rsqrtf(ss);
    unsigned short* o = outb + (size_t)row * N_PIX;
    #pragma unroll
    for (int it = 0; it < 7; ++it) {
        int j = tid + it * 256;
        if (j < N_PIX) o[j] = f2bf((v[it] - mean) * rn);
    }
}

// ---- async 16B global->LDS ----
__device__ __forceinline__ void glds16(const unsigned short* g, char* l) {
    __builtin_amdgcn_global_load_lds(
        (const __attribute__((address_space(1))) void*)(const void*)g,
        (__attribute__((address_space(3))) void*)(void*)l, 16, 0, 0);
}

// raw barrier: no vmcnt drain (the whole point), with compiler fences
#define BAR() do { asm volatile("" ::: "memory"); \
                   __builtin_amdgcn_s_barrier(); \
                   __builtin_amdgcn_sched_barrier(0); } while (0)

// ---- bf16 GEMM, 256x256 tile, 16 waves, counted-vmcnt 4-phase pipeline ----
//
// REGISTER BUDGET (rounds 1-3 post-mortem): the backend consistently budgets
// 128 VGPRs/wave (4-waves/SIMD target) for this kernel; __launch_bounds__ and
// amdgpu_waves_per_eu both failed to raise it (VGPR_Count pinned at 128,
// ~530MB scratch spill of the 128-reg accumulator, MfmaUtil 13%). So this
// version FITS the 128 budget: 16 waves (1024 thr), each wave owns a 64x64
// output sub-tile -> acc = 4x4xf32x4 = 64 regs, + 4 A-frags + 2 B-frags
// + addressing ~= 110 regs. Runtime occupancy 16 waves/CU = 4/SIMD.
//
// LDS layout per buffer p (A then B, 32KB each), split by k-half h (32 cols):
//   byte(p, mat, h, row, slot) = p*65536 + mat*32768 + h*16384 + row*64 + slot*16
// stored slot = chunk ^ ((row>>1)&3) (chunk = 16B unit of the k-half).
// global_load_lds writes linearly (wave base + lane*16); the swizzle is applied
// by permuting the per-lane GLOBAL source chunk (both-sides-or-neither rule).
// Each 16KB region is staged by 16 waves x 1 glds16 (wave w -> rows w*16..+15).
//
// Pipeline per K-tile t (buf p = t&1), staging tile t+1 into p^1.
// Invariant at tile-t entry: outstanding = {A_t_k1, B_t_k1} (2 loads).
//   ph1 (ks=0,jh=0): read A[0..3][0], B[0..1][0]; stage A-k0(t+1);            bar; 8 MFMA; bar
//   ph2 (ks=0,jh=1): read B[2..3][0];             stage B-k0(t+1); vmcnt(2);  bar; 8 MFMA; bar
//   ph3 (ks=1,jh=0): read A[0..3][1], B[0..1][1]; stage A-k1(t+1);            bar; 8 MFMA; bar
//   ph4 (ks=1,jh=1): read B[2..3][1];             stage B-k1(t+1); vmcnt(2);  bar; 8 MFMA; bar
// ph2's vmcnt(2) drains {A_t_k1,B_t_k1} before ph3 reads k1; ph4's vmcnt(2)
// drains {A_{t+1}_k0,B_{t+1}_k0} before next ph1 reads them. The barrier after
// each wait makes per-wave vmcnt a block-wide guarantee. Never vmcnt(0) in
// the main loop; tail tile drains once at its ph2.
__global__
__attribute__((amdgpu_flat_work_group_size(1024, 1024), amdgpu_waves_per_eu(4, 4)))
void gemm_topk(const unsigned short* __restrict__ A,
               const unsigned short* __restrict__ B,
               float* __restrict__ cand_s,
               int* __restrict__ cand_i) {
    extern __shared__ char smem[];

    const int tid  = threadIdx.x;
    const int lane = tid & 63;
    const int w    = tid >> 6;        // 0..15
    const int wm   = w >> 2;          // 0..3 : 64-row band
    const int wn   = w & 3;           // 0..3 : 64-col band
    const int m    = lane & 15;
    const int quad = lane >> 4;

    // XCD-aware swizzle (bijective: 2048 % 8 == 0). 8 consecutive blocks on
    // one XCD share bn -> 819KB B-panel reused from that XCD's L2.
    const int id  = blockIdx.x;
    const int xcd = id & 7;
    const int j_  = id >> 3;          // 0..255
    const int bm  = j_ & 7;           // 8 row tiles
    const int bn  = (j_ >> 3) * 8 + xcd;   // 0..255

    const unsigned short* Ag = A + (size_t)bm * BM * N_PIX;
    const unsigned short* Bg = B + (size_t)bn * BN * N_PIX;

    // staging: per-lane global source (pre-swizzled chunk), wave-uniform LDS dest
    const int srow = w * 16 + (lane >> 2);                    // 0..255
    const int scol = ((lane & 3) ^ ((lane >> 3) & 3)) * 8;    // swizzled source chunk
    const unsigned short* sA = Ag + (size_t)srow * N_PIX + scol;
    const unsigned short* sB = Bg + (size_t)srow * N_PIX + scol;
    char* dst0 = smem + w * 1024;

    // ds_read lane offsets (bytes)
    const int chunk = (quad ^ ((m >> 1) & 3)) * 16;
    const int aoff  = (wm * 64 + m) * 64 + chunk;             // + i*1024 + ks*16384 + p*65536
    const int boff  = 32768 + (wn * 64 + m) * 64 + chunk;     // + j*1024 + ks*16384 + p*65536

    f32x4 acc[4][4];
    #pragma unroll
    for (int i = 0; i < 4; ++i)
        #pragma unroll
        for (int j = 0; j < 4; ++j)
            acc[i][j] = (f32x4){0.f, 0.f, 0.f, 0.f};

    bf16x8 af[4];
    bf16x8 bf2[2];

#define STAGE(MAT, P, H, T) do {                                              \
    const unsigned short* _s = ((MAT) ? sB : sA) + (T) * 64 + (H) * 32;       \
    char* _d = dst0 + (P) * 65536 + (MAT) * 32768 + (H) * 16384;              \
    glds16(_s, _d);                                                           \
} while (0)

#define PHASE(P, KS, JH, DO, SM, SH, ST, VM) do {                                           \
    if ((JH) == 0) {                                                                        \
        _Pragma("unroll")                                                                   \
        for (int i_ = 0; i_ < 4; ++i_)                                                      \
            af[i_] = *(const bf16x8*)(smem + (P)*65536 + (KS)*16384 + i_*1024 + aoff);      \
    }                                                                                       \
    bf2[0] = *(const bf16x8*)(smem + (P)*65536 + (KS)*16384 + ((JH)*2+0)*1024 + boff);      \
    bf2[1] = *(const bf16x8*)(smem + (P)*65536 + (KS)*16384 + ((JH)*2+1)*1024 + boff);      \
    if (DO) STAGE(SM, (P)^1, SH, ST);                                                       \
    if ((VM) == 2) asm volatile("s_waitcnt vmcnt(2)" ::: "memory");                         \
    if ((VM) == 0) asm volatile("s_waitcnt vmcnt(0)" ::: "memory");                         \
    BAR();                                                                                  \
    __builtin_amdgcn_s_setprio(1);                                                          \
    _Pragma("unroll")                                                                       \
    for (int i_ = 0; i_ < 4; ++i_) {                                                        \
        acc[i_][(JH)*2+0] = __builtin_amdgcn_mfma_f32_16x16x32_bf16(af[i_], bf2[0],         \
                                                       acc[i_][(JH)*2+0], 0, 0, 0);         \
        acc[i_][(JH)*2+1] = __builtin_amdgcn_mfma_f32_16x16x32_bf16(af[i_], bf2[1],         \
                                                       acc[i_][(JH)*2+1], 0, 0, 0);         \
    }                                                                                       \
    __builtin_amdgcn_s_setprio(0);                                                          \
    BAR();                                                                                  \
} while (0)

    // prologue: tile 0 fully staged; keep {A-k1(0), B-k1(0)} in flight
    STAGE(0, 0, 0, 0);   // A-k0(0)
    STAGE(1, 0, 0, 0);   // B-k0(0)
    STAGE(0, 0, 1, 0);   // A-k1(0)
    STAGE(1, 0, 1, 0);   // B-k1(0)
    asm volatile("s_waitcnt vmcnt(2)" ::: "memory");
    BAR();

    #pragma unroll 1
    for (int t2 = 0; t2 < 12; ++t2) {
        const int t0 = 2 * t2;
        // tile t0 (buf 0), staging tile t0+1
        PHASE(0, 0, 0, 1, 0, 0, t0 + 1, -1);
        PHASE(0, 0, 1, 1, 1, 0, t0 + 1,  2);
        PHASE(0, 1, 0, 1, 0, 1, t0 + 1, -1);
        PHASE(0, 1, 1, 1, 1, 1, t0 + 1,  2);
        // tile t0+1 (buf 1), staging tile t0+2
        PHASE(1, 0, 0, 1, 0, 0, t0 + 2, -1);
        PHASE(1, 0, 1, 1, 1, 0, t0 + 2,  2);
        PHASE(1, 1, 0, 1, 0, 1, t0 + 2, -1);
        PHASE(1, 1, 1, 1, 1, 1, t0 + 2,  2);
    }
    // tail: tile 24 (buf 0), no prefetch; drain all at its ph2
    PHASE(0, 0, 0, 0, 0, 0, 0, -1);
    PHASE(0, 0, 1, 0, 0, 0, 0,  0);
    PHASE(0, 1, 0, 0, 0, 0, 0, -1);
    PHASE(0, 1, 1, 0, 0, 0, 0, -1);

#undef PHASE
#undef STAGE

    // --- fused epilogue: per-row top-8 of this block's 256 cols ---
    // D layout: col = wn*64 + j*16 + m; row = wm*64 + i*16 + quad*4 + r
    float* Ss = (float*)smem;               // 128 x 256 f32, skewed = 128KB
    const int row4 = tid >> 3;              // 0..127 (row within current half)
    const int part = tid & 7;               // eighth of the 256 cols

    #pragma unroll
    for (int half = 0; half < 2; ++half) {
        __syncthreads();
        if ((wm >> 1) == half) {
            #pragma unroll
            for (int i = 0; i < 4; ++i)
                #pragma unroll
                for (int r = 0; r < 4; ++r) {
                    int row = (wm & 1) * 64 + i * 16 + quad * 4 + r;   // 0..127
                    #pragma unroll
                    for (int j = 0; j < 4; ++j) {
                        int col = wn * 64 + j * 16 + m;
                        Ss[row * 256 + ((col + row) & 255)] = acc[i][j][r];
                    }
                }
        }
        __syncthreads();
        float bs[8]; int bi[8];
        #pragma unroll
        for (int t = 0; t < 8; ++t) { bs[t] = -2.0f; bi[t] = 0; }
        #pragma unroll
        for (int k = 0; k < 32; ++k) {
            int col = part * 32 + ((k + 4 * part) & 31);
            float v = Ss[row4 * 256 + ((col + row4) & 255)];
            if (v > bs[7]) {
                int cix = bn * 256 + col;
                #pragma unroll
                for (int t = 0; t < 8; ++t) {
                    bool sw = v > bs[t];
                    float ts = bs[t]; int ti = bi[t];
                    bs[t] = sw ? v : ts;  bi[t] = sw ? cix : ti;
                    v = sw ? ts : v;      cix = sw ? ti : cix;
                }
            }
        }
        // butterfly merge across the 8 parts (adjacent lanes)
        #pragma unroll
        for (int s = 1; s <= 4; s <<= 1) {
            float ov[8]; int oi[8];
            #pragma unroll
            for (int t = 0; t < 8; ++t) {
                ov[t] = __shfl_xor(bs[t], s);
                oi[t] = __shfl_xor(bi[t], s);
            }
            float rv[8]; int ri[8]; int pa = 0, pb = 0;
            #pragma unroll
            for (int t = 0; t < 8; ++t) {
                float va = sel8f(bs, pa), vb = sel8f(ov, pb);
                bool ta = (va >= vb);
                rv[t] = ta ? va : vb;
                ri[t] = ta ? sel8i(bi, pa) : sel8i(oi, pb);
                pa += ta ? 1 : 0; pb += ta ? 0 : 1;
            }
            #pragma unroll
            for (int t = 0; t < 8; ++t) { bs[t] = rv[t]; bi[t] = ri[t]; }
        }
        if (part == 0) {
            int grow = bm * BM + half * 128 + row4;
            size_t base = (size_t)grow * NCAND + bn * 8;
            *(float4*)(cand_s + base)     = make_float4(bs[0], bs[1], bs[2], bs[3]);
            *(float4*)(cand_s + base + 4) = make_float4(bs[4], bs[5], bs[6], bs[7]);
            *(int4*)(cand_i + base)       = make_int4(bi[0], bi[1], bi[2], bi[3]);
            *(int4*)(cand_i + base + 4)   = make_int4(bi[4], bi[5], bi[6], bi[7]);
        }
    }
}

// ---------------- per-row merge of NCAND candidates -> top-K1 indices ----------------
__global__ __launch_bounds__(256) void merge_cands(const float* __restrict__ cand_s,
                                                   const int* __restrict__ cand_i,
                                                   int* __restrict__ sel_g) {
    __shared__ float Ms[256 * K1];
    __shared__ int   Mi[256 * K1];
    const int row = blockIdx.x, tid = threadIdx.x;
    const float* s = cand_s + (size_t)row * NCAND;
    const int*   x = cand_i + (size_t)row * NCAND;

    float ls[KTH]; int li[KTH];
    #pragma unroll
    for (int t = 0; t < KTH; ++t) { ls[t] = -2.f; li[t] = 0; }
    #pragma unroll
    for (int it = 0; it < NCAND / 256; ++it) {
        int j = tid + it * 256;
        float v = s[j];
        if (v > ls[KTH - 1]) {
            float cv = v; int ci = x[j];
            #pragma unroll
            for (int t = 0; t < KTH; ++t) {
                bool sw = cv > ls[t];
                float ts = ls[t]; int ti = li[t];
                ls[t] = sw ? cv : ts; li[t] = sw ? ci : ti;
                cv = sw ? ts : cv;   ci = sw ? ti : ci;
            }
        }
    }
    #pragma unroll
    for (int t = 0; t < KTH; ++t) { Ms[tid * K1 + t] = ls[t]; Mi[tid * K1 + t] = li[t]; }
    #pragma unroll
    for (int t = KTH; t < K1; ++t) { Ms[tid * K1 + t] = -3.f; Mi[tid * K1 + t] = 0; }
    __syncthreads();

    #pragma unroll
    for (int lev = 0; lev < 8; ++lev) {
        int stride = 1 << lev;
        if ((tid & (2 * stride - 1)) == 0) {
            int ia = tid * K1, ib = (tid + stride) * K1;
            float rs[K1]; int ri[K1];
            int pa = 0, pb = 0;
            #pragma unroll
            for (int t = 0; t < K1; ++t) {
                float va = Ms[ia + pa], vb = Ms[ib + pb];
                bool ta = (va >= vb);
                rs[t] = ta ? va : vb;
                ri[t] = ta ? Mi[ia + pa] : Mi[ib + pb];
                pa += ta ? 1 : 0; pb += ta ? 0 : 1;
            }
            #pragma unroll
            for (int t = 0; t < K1; ++t) { Ms[ia + t] = rs[t]; Mi[ia + t] = ri[t]; }
        }
        __syncthreads();
    }
    if (tid < K1) sel_g[(size_t)row * K1 + tid] = Mi[tid];
}

// ---------------- fp64 rescoring of K2 candidates + outputs ----------------
__global__ __launch_bounds__(256) void refine_out(const float* __restrict__ expd,
                                                  const float* __restrict__ pat,
                                                  const float* __restrict__ so3,
                                                  const int* __restrict__ sel_g,
                                                  float* __restrict__ out) {
    __shared__ double qc[N_PIX];
    __shared__ double pd[4], pd2[4], pd3[4];
    __shared__ int    sel[K2];
    __shared__ double cosv[K2];
    const int row = blockIdx.x, tid = threadIdx.x;
    const float* x = expd + (size_t)row * N_PIX;

    double s1 = 0.0;
    for (int j = tid; j < N_PIX; j += 256) s1 += (double)x[j];
    #pragma unroll
    for (int o = 32; o > 0; o >>= 1) s1 += __shfl_down(s1, o);
    if ((tid & 63) == 0) pd[tid >> 6] = s1;
    __syncthreads();
    const double mean = (pd[0] + pd[1] + pd[2] + pd[3]) * (1.0 / N_PIX);

    double s2 = 0.0, sc = 0.0;
    for (int j = tid; j < N_PIX; j += 256) {
        double c = (double)x[j] - mean;
        qc[j] = c; s2 += c * c; sc += c;
    }
    #pragma unroll
    for (int o = 32; o > 0; o >>= 1) { s2 += __shfl_down(s2, o); sc += __shfl_down(sc, o); }
    if ((tid & 63) == 0) { pd2[tid >> 6] = s2; pd3[tid >> 6] = sc; }
    if (tid < K2) sel[tid] = sel_g[(size_t)row * K2 + tid];
    __syncthreads();
    const double sumsq = pd2[0] + pd2[1] + pd2[2] + pd2[3];
    const double sqc   = pd3[0] + pd3[1] + pd3[2] + pd3[3];
    const double invq  = 1.0 / sqrt(sumsq);

    // fp64 exact cos for each selected candidate: 16 threads per candidate
    const int c  = tid >> 4;
    const int sl = tid & 15;
    const int di = sel[c];
    const float* p = pat + (size_t)di * N_PIX;
    double sp = 0.0, spp = 0.0, sqp = 0.0;
    for (int j = sl; j < N_PIX; j += 16) {
        double pv = (double)p[j];
        sp += pv; spp += pv * pv; sqp += qc[j] * pv;
    }
    #pragma unroll
    for (int o = 8; o > 0; o >>= 1) {
        sp  += __shfl_down(sp,  o, 16);
        spp += __shfl_down(spp, o, 16);
        sqp += __shfl_down(sqp, o, 16);
    }
    if (sl == 0) {
        double mp   = sp * (1.0 / N_PIX);
        double varp = spp - sp * sp * (1.0 / N_PIX);
        double invd = 1.0 / sqrt(varp);
        cosv[c] = (sqp - mp * sqc) * invq * invd;
    }
    __syncthreads();

    if (tid == 0) {
        double cv[K2]; int ci[K2];
        for (int t = 0; t < K2; ++t) { cv[t] = cosv[t]; ci[t] = sel[t]; }
        for (int a = 1; a < K2; ++a) {
            double kv = cv[a]; int ki = ci[a];
            int b = a - 1;
            while (b >= 0 && (cv[b] < kv || (cv[b] == kv && ci[b] > ki))) {
                cv[b + 1] = cv[b]; ci[b + 1] = ci[b]; --b;
            }
            cv[b + 1] = kv; ci[b + 1] = ki;
        }
        float* oa = out;
        float* oi = out + (size_t)N_EXP * TOPK;
        float* oo = out + (size_t)2 * N_EXP * TOPK;
        for (int r = 0; r < TOPK; ++r) {
            double cc = cv[r];
            if (cc > 1.0) cc = 1.0;
            if (cc < -1.0) cc = -1.0;
            oa[(size_t)row * TOPK + r] = (float)acos(cc);
            oi[(size_t)row * TOPK + r] = (float)ci[r];
            int q4 = ci[r];
            #pragma unroll
            for (int t = 0; t < 4; ++t)
                oo[((size_t)row * TOPK + r) * 4 + t] = so3[(size_t)q4 * 4 + t];
        }
    }
}

extern "C" void kernel_launch(void* const* d_in, const int* in_sizes, int n_in,
                              void* d_out, int out_size, void* d_ws, size_t ws_size,
                              hipStream_t stream) {
    const float* expd = (const float*)d_in[0];
    const float* pat  = (const float*)d_in[1];
    const float* so3  = (const float*)d_in[2];
    float* out = (float*)d_out;
    char* ws = (char*)d_ws;

    static bool attr_set = false;
    if (!attr_set) {
        (void)hipFuncSetAttribute((const void*)gemm_topk,
                                  hipFuncAttributeMaxDynamicSharedMemorySize, 131072);
        attr_set = true;
    }

    const size_t QB = (size_t)N_EXP  * N_PIX * 2;      //   6.6 MB bf16 queries
    const size_t DB = (size_t)N_DICT * N_PIX * 2;      // 209.7 MB bf16 dict
    const size_t CB = (size_t)N_EXP  * NCAND * 4;      //  16.8 MB cand scores

    unsigned short* Qb = (unsigned short*)ws;
    unsigned short* Db = (unsigned short*)(ws + QB);
    float* cs  = (float*)(ws + QB + DB);
    int*   ci  = (int*)  (ws + QB + DB + CB);
    int*   sel = (int*)  (ws + QB + DB + 2 * CB);

    prep_rows<<<N_EXP, 256, 0, stream>>>(expd, Qb);
    prep_rows<<<N_DICT, 256, 0, stream>>>(pat, Db);
    gemm_topk<<<(N_EXP / BM) * (N_DICT / BN), 1024, 131072, stream>>>(Qb, Db, cs, ci);
    merge_cands<<<N_EXP, 256, 0, stream>>>(cs, ci, sel);
    refine_out<<<N_EXP, 256, 0, stream>>>(expd, pat, so3, sel, out);
}

// Round 5
// 1277.590 us; speedup vs baseline: 2.0066x; 2.0066x over previous
//
#include <hip/hip_runtime.h>
#include <stdint.h>

#define N_EXP  2048
#define N_DICT 65536
#define N_PIX  1600
#define TOPK   10
#define K1     16     // merged candidate list per row
#define KTH    8      // per-thread top list in merge kernel
#define K2     16     // refine set size
#define NBLK   512    // N_DICT / BN
#define NCAND  (NBLK * 4)   // candidates per row from gemm epilogue

#define BM 128
#define BN 128
#define BK 64
#define KTILES (N_PIX / BK)   // 25

typedef __attribute__((ext_vector_type(8))) __bf16 bf16x8;
typedef __attribute__((ext_vector_type(4))) float  f32x4;

// float -> bf16 (RNE)
__device__ __forceinline__ unsigned short f2bf(float f) {
    unsigned int u = __float_as_uint(f);
    unsigned int r = (u + 0x7FFFu + ((u >> 16) & 1u)) >> 16;
    return (unsigned short)r;
}

__device__ __forceinline__ float sel4f(const float a[4], int p) {
    return p == 0 ? a[0] : (p == 1 ? a[1] : (p == 2 ? a[2] : a[3]));
}
__device__ __forceinline__ int sel4i(const int a[4], int p) {
    return p == 0 ? a[0] : (p == 1 ? a[1] : (p == 2 ? a[2] : a[3]));
}

__device__ __forceinline__ float blockReduceSumF(float v) {
    __shared__ float p[4];
    #pragma unroll
    for (int o = 32; o > 0; o >>= 1) v += __shfl_down(v, o);
    __syncthreads();
    if ((threadIdx.x & 63) == 0) p[threadIdx.x >> 6] = v;
    __syncthreads();
    return p[0] + p[1] + p[2] + p[3];
}

// ---------------- prep: mean-subtract + normalize -> bf16 ----------------
__global__ __launch_bounds__(256) void prep_rows(const float* __restrict__ in,
                                                 unsigned short* __restrict__ outb) {
    const int row = blockIdx.x;
    const int tid = threadIdx.x;
    const float* x = in + (size_t)row * N_PIX;
    float v[7];
    float s = 0.f;
    #pragma unroll
    for (int it = 0; it < 7; ++it) {
        int j = tid + it * 256;
        float t = (j < N_PIX) ? x[j] : 0.f;
        v[it] = t; s += t;
    }
    s = blockReduceSumF(s);
    const float mean = s * (1.0f / N_PIX);
    float ss = 0.f;
    #pragma unroll
    for (int it = 0; it < 7; ++it) {
        int j = tid + it * 256;
        float c = v[it] - mean;
        if (j < N_PIX) ss += c * c;
    }
    ss = blockReduceSumF(ss);
    const float rn = rsqrtf(ss);
    unsigned short* o = outb + (size_t)row * N_PIX;
    #pragma unroll
    for (int it = 0; it < 7; ++it) {
        int j = tid + it * 256;
        if (j < N_PIX) o[j] = f2bf((v[it] - mean) * rn);
    }
}

// ---- async 16B global->LDS ----
__device__ __forceinline__ void glds16(const unsigned short* g, char* l) {
    __builtin_amdgcn_global_load_lds(
        (const __attribute__((address_space(1))) void*)(const void*)g,
        (__attribute__((address_space(3))) void*)(void*)l, 16, 0, 0);
}

// raw barrier with compiler fences (memory clobber orders mem ops; sched_barrier
// stops any hoist/sink across it)
#define BAR() do { asm volatile("" ::: "memory"); \
                   __builtin_amdgcn_s_barrier(); \
                   __builtin_amdgcn_sched_barrier(0); } while (0)

// ---- bf16 GEMM with fused per-row top-4 epilogue ----
//
// R0 structure (proven spill-free: static LDS + 256 thr -> compiler allocates
// ~104 VGPRs, no scratch) + double-buffered staging with counted vmcnt.
// ROUNDS 1-4 LESSON: dynamic LDS (LDS_Block_Size=0 at compile time) makes the
// backend's occupancy heuristic cap VGPRs (128 or 64/wave) and spill the MFMA
// accumulator (0.5-2.6 GB scratch traffic/dispatch). __launch_bounds__ and
// amdgpu_waves_per_eu could not override it. STATIC __shared__ is the only
// configuration observed to allocate registers sanely. Keep it static.
//
// LDS: 2 buffers x (16KB A + 16KB B) = 64KB static. Element chunk kc (16B) of
// row r lives at byte r*128 + (kc ^ (r&7))*16 (XOR swizzle, applied by
// permuting the per-lane GLOBAL source chunk; LDS dest stays linear).
//
// K-loop per tile t (buf p = t&1), 2 barriers/tile like R0 but no full drain:
//   [issue 8 glds16 staging tile t+1 -> buf p^1]   (p^1's readers = tile t-1,
//                                                   separated by t-1's end bar)
//   vmcnt(8)   -> drains tile t's 8 loads (issued one full tile earlier),
//                 keeps tile t+1's 8 in flight across the barrier
//   BAR        -> per-wave drain becomes block-wide guarantee
//   ds_read + 32 MFMA from buf p (compiler handles lgkmcnt)
//   BAR        -> separates buf-p reads from next iteration's staging into p
// Tail tile: no staging, vmcnt(0) once.
__global__ __launch_bounds__(256) void gemm_topk(const unsigned short* __restrict__ A,
                                                 const unsigned short* __restrict__ B,
                                                 float* __restrict__ cand_s,
                                                 int* __restrict__ cand_i) {
    __shared__ __attribute__((aligned(16))) char smem[65536];
    float* Ss = (float*)smem;   // epilogue reuse: 64 x 128 f32

    const int tid  = threadIdx.x;
    const int lane = tid & 63;
    const int w    = tid >> 6;
    const int wm   = w >> 1, wn = w & 1;

    // XCD-aware swizzle: the 16 bm-blocks of one bn stay on one XCD.
    const int id  = blockIdx.x;
    const int xcd = id & 7;
    const int j_  = id >> 3;            // 0..1023 per-XCD sequence
    const int bm  = j_ & 15;
    const int bn  = (j_ >> 4) * 8 + xcd;

    const unsigned short* Ag = A + (size_t)bm * BM * N_PIX;
    const unsigned short* Bg = B + (size_t)bn * BN * N_PIX;

    const int ldr = lane >> 3;                      // row within 8-row chunk (== r&7)
    const int ldc = (((lane & 7) ^ ldr) * 8);       // swizzled source col chunk
    const int m    = lane & 15;
    const int quad = lane >> 4;

    f32x4 acc[4][4];
    #pragma unroll
    for (int i = 0; i < 4; ++i)
        #pragma unroll
        for (int j = 0; j < 4; ++j)
            acc[i][j] = (f32x4){0.f, 0.f, 0.f, 0.f};

    // stage K-tile T (k0 = T*BK) into buffer P (8 glds16 per thread)
#define STAGE_TILE(P, T) do {                                                     \
    const int _k0 = (T) * BK;                                                     \
    _Pragma("unroll")                                                             \
    for (int t_ = 0; t_ < 4; ++t_) {                                              \
        int r_ = w * 32 + t_ * 8 + ldr;                                           \
        glds16(Ag + (size_t)r_ * N_PIX + _k0 + ldc,                               \
               smem + (P) * 32768 + (w * 4 + t_) * 1024);                         \
        glds16(Bg + (size_t)r_ * N_PIX + _k0 + ldc,                               \
               smem + (P) * 32768 + 16384 + (w * 4 + t_) * 1024);                 \
    }                                                                             \
} while (0)

    // prologue: stage tile 0 into buf 0 (8 loads in flight)
    STAGE_TILE(0, 0);

    #pragma unroll 1
    for (int kt = 0; kt < KTILES; ++kt) {
        const int p = kt & 1;
        if (kt + 1 < KTILES) {
            STAGE_TILE(p ^ 1, kt + 1);
            asm volatile("s_waitcnt vmcnt(8)" ::: "memory");
        } else {
            asm volatile("s_waitcnt vmcnt(0)" ::: "memory");
        }
        BAR();
        const unsigned short* As = (const unsigned short*)(smem + p * 32768);
        const unsigned short* Bs = (const unsigned short*)(smem + p * 32768 + 16384);
        #pragma unroll
        for (int ks = 0; ks < BK; ks += 32) {
            bf16x8 af[4], bfr[4];
            const int kc = (ks >> 3) + quad;        // 16B chunk index within row
            const int sw = (kc ^ (m & 7)) * 8;      // swizzled element offset
            #pragma unroll
            for (int i = 0; i < 4; ++i)
                af[i] = *(const bf16x8*)(&As[(wm * 64 + i * 16 + m) * BK + sw]);
            #pragma unroll
            for (int j = 0; j < 4; ++j)
                bfr[j] = *(const bf16x8*)(&Bs[(wn * 64 + j * 16 + m) * BK + sw]);
            #pragma unroll
            for (int i = 0; i < 4; ++i)
                #pragma unroll
                for (int j = 0; j < 4; ++j)
                    acc[i][j] = __builtin_amdgcn_mfma_f32_16x16x32_bf16(af[i], bfr[j], acc[i][j], 0, 0, 0);
        }
        BAR();
    }
#undef STAGE_TILE

    // --- fused epilogue: per-row top-4 of this block's 128 cols ---
    // D layout: col = wn*64 + j*16 + m; row = wm*64 + i*16 + quad*4 + r
    const int row4 = tid >> 2;   // 0..63 (row within current half)
    const int part = tid & 3;    // quarter of the 128 cols

    #pragma unroll
    for (int half = 0; half < 2; ++half) {
        __syncthreads();
        if (wm == half) {
            #pragma unroll
            for (int i = 0; i < 4; ++i)
                #pragma unroll
                for (int r = 0; r < 4; ++r) {
                    int row = i * 16 + quad * 4 + r;       // 0..63
                    #pragma unroll
                    for (int j = 0; j < 4; ++j) {
                        int col = wn * 64 + j * 16 + m;
                        Ss[row * 128 + ((col + row) & 127)] = acc[i][j][r];
                    }
                }
        }
        __syncthreads();
        float bs4[4]; int bi4[4];
        bs4[0] = bs4[1] = bs4[2] = bs4[3] = -2.0f;
        bi4[0] = bi4[1] = bi4[2] = bi4[3] = 0;
        #pragma unroll
        for (int k = 0; k < 32; ++k) {
            int col = part * 32 + ((k + 8 * part) & 31);
            float v = Ss[row4 * 128 + ((col + row4) & 127)];
            if (v > bs4[3]) {
                int cix = bn * 128 + col;
                #pragma unroll
                for (int t = 0; t < 4; ++t) {
                    bool sw = v > bs4[t];
                    float ts = bs4[t]; int ti = bi4[t];
                    bs4[t] = sw ? v : ts;  bi4[t] = sw ? cix : ti;
                    v = sw ? ts : v;       cix = sw ? ti : cix;
                }
            }
        }
        // butterfly merge across the 4 parts (adjacent lanes)
        #pragma unroll
        for (int s = 1; s <= 2; s <<= 1) {
            float ov[4]; int oi[4];
            #pragma unroll
            for (int t = 0; t < 4; ++t) {
                ov[t] = __shfl_xor(bs4[t], s);
                oi[t] = __shfl_xor(bi4[t], s);
            }
            float rv[4]; int ri[4]; int pa = 0, pb = 0;
            #pragma unroll
            for (int t = 0; t < 4; ++t) {
                float va = sel4f(bs4, pa), vb = sel4f(ov, pb);
                bool ta = (va >= vb);
                rv[t] = ta ? va : vb;
                ri[t] = ta ? sel4i(bi4, pa) : sel4i(oi, pb);
                pa += ta ? 1 : 0; pb += ta ? 0 : 1;
            }
            #pragma unroll
            for (int t = 0; t < 4; ++t) { bs4[t] = rv[t]; bi4[t] = ri[t]; }
        }
        if (part == 0) {
            int grow = bm * BM + half * 64 + row4;
            *(float4*)(cand_s + (size_t)grow * NCAND + bn * 4) =
                make_float4(bs4[0], bs4[1], bs4[2], bs4[3]);
            *(int4*)(cand_i + (size_t)grow * NCAND + bn * 4) =
                make_int4(bi4[0], bi4[1], bi4[2], bi4[3]);
        }
    }
}

// ---------------- per-row merge of NCAND candidates -> top-K1 indices ----------------
__global__ __launch_bounds__(256) void merge_cands(const float* __restrict__ cand_s,
                                                   const int* __restrict__ cand_i,
                                                   int* __restrict__ sel_g) {
    __shared__ float Ms[256 * K1];
    __shared__ int   Mi[256 * K1];
    const int row = blockIdx.x, tid = threadIdx.x;
    const float* s = cand_s + (size_t)row * NCAND;
    const int*   x = cand_i + (size_t)row * NCAND;

    float ls[KTH]; int li[KTH];
    #pragma unroll
    for (int t = 0; t < KTH; ++t) { ls[t] = -2.f; li[t] = 0; }
    #pragma unroll
    for (int it = 0; it < NCAND / 256; ++it) {
        int j = tid + it * 256;
        float v = s[j];
        if (v > ls[KTH - 1]) {
            float cv = v; int ci = x[j];
            #pragma unroll
            for (int t = 0; t < KTH; ++t) {
                bool sw = cv > ls[t];
                float ts = ls[t]; int ti = li[t];
                ls[t] = sw ? cv : ts; li[t] = sw ? ci : ti;
                cv = sw ? ts : cv;   ci = sw ? ti : ci;
            }
        }
    }
    #pragma unroll
    for (int t = 0; t < KTH; ++t) { Ms[tid * K1 + t] = ls[t]; Mi[tid * K1 + t] = li[t]; }
    #pragma unroll
    for (int t = KTH; t < K1; ++t) { Ms[tid * K1 + t] = -3.f; Mi[tid * K1 + t] = 0; }
    __syncthreads();

    #pragma unroll
    for (int lev = 0; lev < 8; ++lev) {
        int stride = 1 << lev;
        if ((tid & (2 * stride - 1)) == 0) {
            int ia = tid * K1, ib = (tid + stride) * K1;
            float rs[K1]; int ri[K1];
            int pa = 0, pb = 0;
            #pragma unroll
            for (int t = 0; t < K1; ++t) {
                float va = Ms[ia + pa], vb = Ms[ib + pb];
                bool ta = (va >= vb);
                rs[t] = ta ? va : vb;
                ri[t] = ta ? Mi[ia + pa] : Mi[ib + pb];
                pa += ta ? 1 : 0; pb += ta ? 0 : 1;
            }
            #pragma unroll
            for (int t = 0; t < K1; ++t) { Ms[ia + t] = rs[t]; Mi[ia + t] = ri[t]; }
        }
        __syncthreads();
    }
    if (tid < K1) sel_g[(size_t)row * K1 + tid] = Mi[tid];
}

// ---------------- fp64 rescoring of K2 candidates + outputs ----------------
__global__ __launch_bounds__(256) void refine_out(const float* __restrict__ expd,
                                                  const float* __restrict__ pat,
                                                  const float* __restrict__ so3,
                                                  const int* __restrict__ sel_g,
                                                  float* __restrict__ out) {
    __shared__ double qc[N_PIX];
    __shared__ double pd[4], pd2[4], pd3[4];
    __shared__ int    sel[K2];
    __shared__ double cosv[K2];
    const int row = blockIdx.x, tid = threadIdx.x;
    const float* x = expd + (size_t)row * N_PIX;

    double s1 = 0.0;
    for (int j = tid; j < N_PIX; j += 256) s1 += (double)x[j];
    #pragma unroll
    for (int o = 32; o > 0; o >>= 1) s1 += __shfl_down(s1, o);
    if ((tid & 63) == 0) pd[tid >> 6] = s1;
    __syncthreads();
    const double mean = (pd[0] + pd[1] + pd[2] + pd[3]) * (1.0 / N_PIX);

    double s2 = 0.0, sc = 0.0;
    for (int j = tid; j < N_PIX; j += 256) {
        double c = (double)x[j] - mean;
        qc[j] = c; s2 += c * c; sc += c;
    }
    #pragma unroll
    for (int o = 32; o > 0; o >>= 1) { s2 += __shfl_down(s2, o); sc += __shfl_down(sc, o); }
    if ((tid & 63) == 0) { pd2[tid >> 6] = s2; pd3[tid >> 6] = sc; }
    if (tid < K2) sel[tid] = sel_g[(size_t)row * K2 + tid];
    __syncthreads();
    const double sumsq = pd2[0] + pd2[1] + pd2[2] + pd2[3];
    const double sqc   = pd3[0] + pd3[1] + pd3[2] + pd3[3];
    const double invq  = 1.0 / sqrt(sumsq);

    // fp64 exact cos for each selected candidate: 16 threads per candidate
    const int c  = tid >> 4;
    const int sl = tid & 15;
    const int di = sel[c];
    const float* p = pat + (size_t)di * N_PIX;
    double sp = 0.0, spp = 0.0, sqp = 0.0;
    for (int j = sl; j < N_PIX; j += 16) {
        double pv = (double)p[j];
        sp += pv; spp += pv * pv; sqp += qc[j] * pv;
    }
    #pragma unroll
    for (int o = 8; o > 0; o >>= 1) {
        sp  += __shfl_down(sp,  o, 16);
        spp += __shfl_down(spp, o, 16);
        sqp += __shfl_down(sqp, o, 16);
    }
    if (sl == 0) {
        double mp   = sp * (1.0 / N_PIX);
        double varp = spp - sp * sp * (1.0 / N_PIX);
        double invd = 1.0 / sqrt(varp);
        cosv[c] = (sqp - mp * sqc) * invq * invd;
    }
    __syncthreads();

    if (tid == 0) {
        double cv[K2]; int ci[K2];
        for (int t = 0; t < K2; ++t) { cv[t] = cosv[t]; ci[t] = sel[t]; }
        for (int a = 1; a < K2; ++a) {
            double kv = cv[a]; int ki = ci[a];
            int b = a - 1;
            while (b >= 0 && (cv[b] < kv || (cv[b] == kv && ci[b] > ki))) {
                cv[b + 1] = cv[b]; ci[b + 1] = ci[b]; --b;
            }
            cv[b + 1] = kv; ci[b + 1] = ki;
        }
        float* oa = out;
        float* oi = out + (size_t)N_EXP * TOPK;
        float* oo = out + (size_t)2 * N_EXP * TOPK;
        for (int r = 0; r < TOPK; ++r) {
            double cc = cv[r];
            if (cc > 1.0) cc = 1.0;
            if (cc < -1.0) cc = -1.0;
            oa[(size_t)row * TOPK + r] = (float)acos(cc);
            oi[(size_t)row * TOPK + r] = (float)ci[r];
            int q4 = ci[r];
            #pragma unroll
            for (int t = 0; t < 4; ++t)
                oo[((size_t)row * TOPK + r) * 4 + t] = so3[(size_t)q4 * 4 + t];
        }
    }
}

extern "C" void kernel_launch(void* const* d_in, const int* in_sizes, int n_in,
                              void* d_out, int out_size, void* d_ws, size_t ws_size,
                              hipStream_t stream) {
    const float* expd = (const float*)d_in[0];
    const float* pat  = (const float*)d_in[1];
    const float* so3  = (const float*)d_in[2];
    float* out = (float*)d_out;
    char* ws = (char*)d_ws;

    const size_t QB = (size_t)N_EXP  * N_PIX * 2;      //   6.6 MB bf16 queries
    const size_t DB = (size_t)N_DICT * N_PIX * 2;      // 209.7 MB bf16 dict
    const size_t CB = (size_t)N_EXP  * NCAND * 4;      //  16.8 MB cand scores

    unsigned short* Qb = (unsigned short*)ws;
    unsigned short* Db = (unsigned short*)(ws + QB);
    float* cs  = (float*)(ws + QB + DB);
    int*   ci  = (int*)  (ws + QB + DB + CB);
    int*   sel = (int*)  (ws + QB + DB + 2 * CB);

    prep_rows<<<N_EXP, 256, 0, stream>>>(expd, Qb);
    prep_rows<<<N_DICT, 256, 0, stream>>>(pat, Db);
    gemm_topk<<<(N_EXP / BM) * (N_DICT / BN), 256, 0, stream>>>(Qb, Db, cs, ci);
    merge_cands<<<N_EXP, 256, 0, stream>>>(cs, ci, sel);
    refine_out<<<N_EXP, 256, 0, stream>>>(expd, pat, so3, sel, out);
}